// Round 1
// 353.645 us; speedup vs baseline: 1.4315x; 1.4315x over previous
//
#include <hip/hip_runtime.h>
#include <hip/hip_bf16.h>
#include <cstdint>

// Sizes
#define Bz 4
#define Tz 256
#define Dz 256
#define D2z 512
#define Hz 4
#define DHz 128
#define BT (Bz*Tz)          // 1024 rows

__device__ __forceinline__ float dot4(float4 a, float4 b){
  return a.x*b.x + a.y*b.y + a.z*b.z + a.w*b.w;
}
__device__ __forceinline__ float sigmoidf_(float z){ return 1.f/(1.f+__expf(-z)); }

// ---------------- LayerNorm: one block per (b,t) row ----------------
__global__ void k_ln(const float* __restrict__ x, const float* __restrict__ g,
                     const float* __restrict__ bb, float* __restrict__ xn){
  int row = blockIdx.x;
  int tid = threadIdx.x;            // 256
  float v = x[(size_t)row*Dz + tid];
  float s = v, s2 = v*v;
  #pragma unroll
  for (int off=32; off; off>>=1){ s += __shfl_down(s, off); s2 += __shfl_down(s2, off); }
  __shared__ float ls[8];
  int wid = tid>>6, lane = tid&63;
  if (lane==0){ ls[wid]=s; ls[4+wid]=s2; }
  __syncthreads();
  if (tid==0){
    float a=ls[0]+ls[1]+ls[2]+ls[3], c=ls[4]+ls[5]+ls[6]+ls[7];
    float mu=a*(1.f/Dz), var=c*(1.f/Dz)-mu*mu;
    ls[0]=mu; ls[1]=rsqrtf(var+1e-5f);
  }
  __syncthreads();
  float mu=ls[0], rs=ls[1];
  xn[(size_t)row*Dz+tid] = (v-mu)*rs*g[tid]+bb[tid];
}

// ---------------- x_left / x_right GEMM: block per 8 rows, 512 thr ----------------
__global__ void k_lr(const float* __restrict__ xn, const float* __restrict__ WL,
                     const float* __restrict__ bL, const float* __restrict__ WR,
                     const float* __restrict__ bR, float* __restrict__ xl,
                     float* __restrict__ xr){
  __shared__ float xs[8][Dz];
  int r0 = blockIdx.x*8;
  int tid = threadIdx.x;            // 512
  ((float4*)&xs[0][0])[tid] = ((const float4*)(xn + (size_t)r0*Dz))[tid];
  __syncthreads();
  int o = tid;
  float accL[8]={0,0,0,0,0,0,0,0}, accR[8]={0,0,0,0,0,0,0,0};
  const float4* wl4 = (const float4*)(WL + (size_t)o*Dz);
  const float4* wr4 = (const float4*)(WR + (size_t)o*Dz);
  for (int k4=0;k4<Dz/4;k4++){
    float4 wl=wl4[k4], wr=wr4[k4];
    #pragma unroll
    for(int tt=0;tt<8;tt++){
      float4 xv = ((const float4*)xs[tt])[k4];
      accL[tt] += dot4(wl,xv);
      accR[tt] += dot4(wr,xv);
    }
  }
  float bl=bL[o], br=bR[o];
  #pragma unroll
  for(int tt=0;tt<8;tt++){
    xl[(size_t)(r0+tt)*D2z+o]=accL[tt]+bl;
    xr[(size_t)(r0+tt)*D2z+o]=accR[tt]+br;
  }
}

// ---------------- i_bar / f_bar: one wave per row ----------------
__global__ void __launch_bounds__(64) k_if(const float* __restrict__ xl,
    const float* __restrict__ Wi,const float* __restrict__ bi,
    const float* __restrict__ Wf,const float* __restrict__ bf,
    float* __restrict__ ib,float* __restrict__ fb){
  int row=blockIdx.x; int lane=threadIdx.x;
  const float4* xp=(const float4*)(xl+(size_t)row*D2z);
  float4 xa=xp[lane*2],xb=xp[lane*2+1];
  const float4* wi=(const float4*)Wi; const float4* wf=(const float4*)Wf;
  float si=dot4(wi[lane*2],xa)+dot4(wi[lane*2+1],xb);
  float sf=dot4(wf[lane*2],xa)+dot4(wf[lane*2+1],xb);
  #pragma unroll
  for(int off=1;off<64;off<<=1){si+=__shfl_xor(si,off);sf+=__shfl_xor(sf,off);}
  if(lane==0){ib[row]=si+bi[0];fb[row]=sf+bf[0];}
}

// ---------------- causal conv1d k=4 + swish: block=(8 t's, 256 o's) ----------------
__global__ void k_conv(const float* __restrict__ xl, const float* __restrict__ CW,
                       const float* __restrict__ cb, float* __restrict__ xt){
  __shared__ float xs[11][D2z];     // rows t0-3 .. t0+7
  int bt8 = blockIdx.x;             // 0..127
  int oh  = blockIdx.y;             // 0..1
  int b = bt8>>5; int t0 = (bt8&31)*8;
  int tid = threadIdx.x;            // 256
  for(int idx=tid; idx<11*(D2z/4); idx+=256){
    int j = idx>>7;                 // row 0..10 (128 float4 per row)
    int k4 = idx&127;
    int t = t0-3+j;
    float4 v = (t>=0) ? ((const float4*)(xl + (size_t)((b<<8)+t)*D2z))[k4]
                      : make_float4(0.f,0.f,0.f,0.f);
    ((float4*)xs[j])[k4]=v;
  }
  __syncthreads();
  int o = oh*256 + tid;
  float acc[8]={0,0,0,0,0,0,0,0};
  const float4* w4=(const float4*)(CW+(size_t)o*2048);  // [i] -> taps 0..3 of chan i
  for(int i=0;i<D2z;i+=2){
    float4 wA=w4[i], wB=w4[i+1];
    float2 xr2[11];
    #pragma unroll
    for(int j=0;j<11;j++) xr2[j]=*(const float2*)&xs[j][i];
    #pragma unroll
    for(int tt=0;tt<8;tt++){
      acc[tt] += wA.x*xr2[tt].x + wA.y*xr2[tt+1].x + wA.z*xr2[tt+2].x + wA.w*xr2[tt+3].x
               + wB.x*xr2[tt].y + wB.y*xr2[tt+1].y + wB.z*xr2[tt+2].y + wB.w*xr2[tt+3].y;
    }
  }
  float cbo = cb[o];
  #pragma unroll
  for(int tt=0;tt<8;tt++){
    float y = acc[tt]+cbo;
    xt[(size_t)((b<<8)+t0+tt)*D2z+o] = y*sigmoidf_(y);
  }
}

// ---------------- o-gate (Wo, sigmoid) + v (block-diag Wv): 4 rows, 2 o/thread ----------------
__global__ void k_wov(const float* __restrict__ xl,const float* __restrict__ Wo,
                      const float* __restrict__ bo,const float* __restrict__ Wv,
                      float* __restrict__ og,float* __restrict__ vv){
  __shared__ float xs[4][D2z];
  int r0=blockIdx.x*4; int tid=threadIdx.x;   // 256
  for(int idx=tid;idx<512;idx+=256)
    ((float4*)&xs[0][0])[idx]=((const float4*)(xl+(size_t)r0*D2z))[idx];
  __syncthreads();
  int o0=tid,o1=tid+256;
  float a0[4]={0,0,0,0},a1[4]={0,0,0,0};
  const float4* w0=(const float4*)(Wo+(size_t)o0*D2z);
  const float4* w1=(const float4*)(Wo+(size_t)o1*D2z);
  for(int i4=0;i4<128;i4++){
    float4 wa=w0[i4],wb=w1[i4];
    #pragma unroll
    for(int tt=0;tt<4;tt++){
      float4 xv=((const float4*)xs[tt])[i4];
      a0[tt]+=dot4(wa,xv); a1[tt]+=dot4(wb,xv);
    }
  }
  float v0[4]={0,0,0,0},v1[4]={0,0,0,0};
  int h0=o0>>7,h1=o1>>7;
  const float4* wv0=(const float4*)Wv+(size_t)o0*32;
  const float4* wv1=(const float4*)Wv+(size_t)o1*32;
  for(int i4=0;i4<32;i4++){
    float4 wa=wv0[i4],wb=wv1[i4];
    #pragma unroll
    for(int tt=0;tt<4;tt++){
      float4 xva=((const float4*)xs[tt])[h0*32+i4];
      float4 xvb=((const float4*)xs[tt])[h1*32+i4];
      v0[tt]+=dot4(wa,xva); v1[tt]+=dot4(wb,xvb);
    }
  }
  float bo0=bo[o0],bo1=bo[o1];
  #pragma unroll
  for(int tt=0;tt<4;tt++){
    size_t row=r0+tt;
    og[row*D2z+o0]=sigmoidf_(a0[tt]+bo0);
    og[row*D2z+o1]=sigmoidf_(a1[tt]+bo1);
    vv[row*D2z+o0]=v0[tt];
    vv[row*D2z+o1]=v1[tt];
  }
}

// ---------------- q,k (block-diag) + skip GEMM from x_trans ----------------
__global__ void k_qks(const float* __restrict__ xt,const float* __restrict__ Wq,
                      const float* __restrict__ Wk,const float* __restrict__ SW,
                      float* __restrict__ qq,float* __restrict__ kk,
                      float* __restrict__ sk){
  __shared__ float xs[4][D2z];
  int r0=blockIdx.x*4; int tid=threadIdx.x;   // 256
  for(int idx=tid;idx<512;idx+=256)
    ((float4*)&xs[0][0])[idx]=((const float4*)(xt+(size_t)r0*D2z))[idx];
  __syncthreads();
  int o0=tid,o1=tid+256;
  float s0[4]={0,0,0,0},s1[4]={0,0,0,0};
  const float4* w0=(const float4*)(SW+(size_t)o0*D2z);
  const float4* w1=(const float4*)(SW+(size_t)o1*D2z);
  for(int i4=0;i4<128;i4++){
    float4 wa=w0[i4],wb=w1[i4];
    #pragma unroll
    for(int tt=0;tt<4;tt++){
      float4 xv=((const float4*)xs[tt])[i4];
      s0[tt]+=dot4(wa,xv); s1[tt]+=dot4(wb,xv);
    }
  }
  float q0[4]={0,0,0,0},q1[4]={0,0,0,0},k0[4]={0,0,0,0},k1[4]={0,0,0,0};
  int h0=o0>>7,h1=o1>>7;
  const float4* wq0=(const float4*)Wq+(size_t)o0*32; const float4* wq1=(const float4*)Wq+(size_t)o1*32;
  const float4* wk0=(const float4*)Wk+(size_t)o0*32; const float4* wk1=(const float4*)Wk+(size_t)o1*32;
  for(int i4=0;i4<32;i4++){
    float4 qa=wq0[i4],qb=wq1[i4],ka=wk0[i4],kb2=wk1[i4];
    #pragma unroll
    for(int tt=0;tt<4;tt++){
      float4 xva=((const float4*)xs[tt])[h0*32+i4];
      float4 xvb=((const float4*)xs[tt])[h1*32+i4];
      q0[tt]+=dot4(qa,xva); q1[tt]+=dot4(qb,xvb);
      k0[tt]+=dot4(ka,xva); k1[tt]+=dot4(kb2,xvb);
    }
  }
  #pragma unroll
  for(int tt=0;tt<4;tt++){
    size_t row=r0+tt;
    qq[row*D2z+o0]=q0[tt];        qq[row*D2z+o1]=q1[tt];
    kk[row*D2z+o0]=0.0625f*k0[tt]; kk[row*D2z+o1]=0.0625f*k1[tt];  // SCALE = D^-0.5
    sk[row*D2z+o0]=s0[tt];        sk[row*D2z+o1]=s1[tt];
  }
}

// ---------------- decay precompute: F = cumsum(fb), G = ib - F, Mx = max(0, cummax(G)) ----------------
// Closed form of the reference's stabilized recurrence:
//   m_t - F_t = max(0, max_{s<=t} (ib_s - F_s))   (m'_t = Mx[t])
//   weight(t,s) = exp(ib_s + F_t - F_s - m_t) = exp(G_s - Mx_t) <= 1
__global__ void __launch_bounds__(256) k_decay(
    const float* __restrict__ ibar, const float* __restrict__ fbar,
    float* __restrict__ G, float* __restrict__ Mx){
  int b = blockIdx.x, t = threadIdx.x;   // 256 threads = Tz
  __shared__ float buf[Tz];
  float f = fbar[b*Tz + t];
  // inclusive prefix sum (Hillis-Steele)
  buf[t] = f; __syncthreads();
  float v = f;
  for (int off=1; off<Tz; off<<=1){
    float add = (t >= off) ? buf[t-off] : 0.f;
    __syncthreads();
    v += add; buf[t] = v;
    __syncthreads();
  }
  float F = v;
  float g = ibar[b*Tz+t] - F;
  G[b*Tz+t] = g;
  // inclusive prefix max
  buf[t] = g; __syncthreads();
  v = g;
  for (int off=1; off<Tz; off<<=1){
    float other = (t >= off) ? buf[t-off] : -3.4e38f;
    __syncthreads();
    v = fmaxf(v, other); buf[t] = v;
    __syncthreads();
  }
  Mx[b*Tz+t] = fmaxf(v, 0.f);
}

// ---------------- scan as causal decayed attention ----------------
// h_t = o_t * (P V)_t / (max(|rowsum(P)_t|,1)+1e-8),  P[t,s] = (q_t.k_s)*exp(G_s - Mx_t), s<=t
#define TTa 8
__global__ void __launch_bounds__(256) k_attn(
    const float* __restrict__ qq, const float* __restrict__ kk,
    const float* __restrict__ vv, const float* __restrict__ og,
    const float* __restrict__ G, const float* __restrict__ Mx,
    float* __restrict__ hs){
  int b  = blockIdx.y;
  int t0 = blockIdx.x * TTa;
  int tid = threadIdx.x;            // 256
  __shared__ float Qs[TTa][D2z];    // 16 KB
  __shared__ float Ps[TTa][Tz];     // 8 KB
  __shared__ float Gs[Tz];          // 1 KB
  __shared__ float inv_d[TTa];
  __shared__ float mxs[TTa];

  const float* qb = qq + ((size_t)b*Tz + t0)*D2z;
  for (int idx=tid; idx<TTa*D2z/4; idx+=256)
    ((float4*)&Qs[0][0])[idx] = ((const float4*)qb)[idx];
  Gs[tid] = G[b*Tz + tid];
  if (tid < TTa) mxs[tid] = Mx[b*Tz + t0 + tid];
  __syncthreads();

  int s = tid;                      // thread owns key/value index s
  int smax = t0 + TTa - 1;          // last causal s needed by this block
  // ---- phase 1: scores S[tt][s] = q_{t0+tt} . k_s, then weight+mask into Ps ----
  {
    float acc[TTa] = {0,0,0,0,0,0,0,0};
    if (s <= smax){
      const float4* kp = (const float4*)(kk + ((size_t)b*Tz + s)*D2z);
      for (int k4=0; k4<D2z/4; k4++){
        float4 kv = kp[k4];
        #pragma unroll
        for (int tt=0; tt<TTa; tt++){
          float4 qv = ((const float4*)Qs[tt])[k4];   // broadcast read
          acc[tt] += dot4(kv,qv);
        }
      }
    }
    float g = Gs[s];
    #pragma unroll
    for (int tt=0; tt<TTa; tt++){
      int t = t0 + tt;
      Ps[tt][s] = (s <= t) ? acc[tt] * __expf(g - mxs[tt]) : 0.f;
    }
  }
  __syncthreads();
  // ---- rowsum -> denom (wave w handles rows 2w, 2w+1) ----
  {
    int wv = tid >> 6, lane = tid & 63;
    #pragma unroll
    for (int r=0; r<2; r++){
      int tt = wv*2 + r;
      float ssum = Ps[tt][lane] + Ps[tt][lane+64] + Ps[tt][lane+128] + Ps[tt][lane+192];
      #pragma unroll
      for (int off=1; off<64; off<<=1) ssum += __shfl_xor(ssum, off);
      if (lane==0) inv_d[tt] = 1.f / (fmaxf(fabsf(ssum), 1.f) + 1e-8f);
    }
  }
  __syncthreads();
  // ---- phase 2: out[tt][c] = sum_s Ps[tt][s] * V[s][c] ----
  {
    int c0 = tid, c1 = tid + 256;
    float a0[TTa]={0,0,0,0,0,0,0,0}, a1[TTa]={0,0,0,0,0,0,0,0};
    const float* vb = vv + (size_t)b*Tz*D2z;
    for (int s2=0; s2<=smax; s2+=4){
      float4 pr[TTa];
      #pragma unroll
      for (int tt=0; tt<TTa; tt++) pr[tt] = *(const float4*)&Ps[tt][s2];  // broadcast b128
      #pragma unroll
      for (int j=0; j<4; j++){
        int sj = s2 + j;
        float v0 = vb[(size_t)sj*D2z + c0];
        float v1 = vb[(size_t)sj*D2z + c1];
        #pragma unroll
        for (int tt=0; tt<TTa; tt++){
          float p = ((const float*)&pr[tt])[j];
          a0[tt] += p*v0; a1[tt] += p*v1;
        }
      }
    }
    #pragma unroll
    for (int tt=0; tt<TTa; tt++){
      size_t row = (size_t)b*Tz + t0 + tt;
      float id = inv_d[tt];
      hs[row*D2z + c0] = og[row*D2z + c0] * a0[tt] * id;
      hs[row*D2z + c1] = og[row*D2z + c1] * a1[tt] * id;
    }
  }
}

// ---------------- GroupNorm stats per (b,h): mean & rstd over (T,DH) ----------------
__global__ void k_gnstat(const float* __restrict__ hs,float* __restrict__ gmu,
                         float* __restrict__ grs){
  int g=blockIdx.x; int b=g>>2,h=g&3; int tid=threadIdx.x;  // 256 thr
  float s=0.f,s2=0.f;
  const float* base=hs+(size_t)b*Tz*D2z+h*DHz;
  for(int idx=tid;idx<Tz*DHz;idx+=256){
    int t=idx>>7,c=idx&127;
    float v=base[(size_t)t*D2z+c];
    s+=v;s2+=v*v;
  }
  #pragma unroll
  for(int off=32;off;off>>=1){s+=__shfl_down(s,off);s2+=__shfl_down(s2,off);}
  __shared__ float ls[8];
  int wid=tid>>6,lane=tid&63;
  if(lane==0){ls[wid]=s;ls[4+wid]=s2;}
  __syncthreads();
  if(tid==0){
    float S=ls[0]+ls[1]+ls[2]+ls[3],S2=ls[4]+ls[5]+ls[6]+ls[7];
    float mu=S*(1.f/(Tz*DHz));
    float var=S2*(1.f/(Tz*DHz))-mu*mu;
    gmu[g]=mu; grs[g]=rsqrtf(fmaxf(var,0.f)+1e-5f);
  }
}

// ---------------- finish: GN apply + skip + *swish(x_right) + W_last GEMM + residual ----------------
__global__ void k_final(const float* __restrict__ hs,const float* __restrict__ gmu,
    const float* __restrict__ grs,const float* __restrict__ gng,
    const float* __restrict__ gnb,const float* __restrict__ sk,
    const float* __restrict__ xr,const float* __restrict__ WL,
    const float* __restrict__ bl,const float* __restrict__ x,
    float* __restrict__ out){
  __shared__ float hm[4][D2z];
  int r0=blockIdx.x*4; int b=r0>>8; int tid=threadIdx.x;   // 256 thr
  for(int idx=tid;idx<4*D2z;idx+=256){
    int tt=idx>>9,c=idx&511;
    size_t row=r0+tt;
    int g=(b<<2)+(c>>7);
    float v=hs[row*D2z+c];
    float hg=(v-gmu[g])*grs[g]*gng[c]+gnb[c]+sk[row*D2z+c];
    float xv=xr[row*D2z+c];
    hm[tt][c]=hg*(xv*sigmoidf_(xv));
  }
  __syncthreads();
  int d=tid;
  float acc[4]={0,0,0,0};
  const float4* w4=(const float4*)(WL+(size_t)d*D2z);
  for(int i4=0;i4<128;i4++){
    float4 w=w4[i4];
    #pragma unroll
    for(int tt=0;tt<4;tt++){
      float4 hv=((const float4*)hm[tt])[i4];
      acc[tt]+=dot4(w,hv);
    }
  }
  float bd=bl[d];
  #pragma unroll
  for(int tt=0;tt<4;tt++){
    size_t row=r0+tt;
    out[row*Dz+d]=acc[tt]+bd+x[row*Dz+d];
  }
}

extern "C" void kernel_launch(void* const* d_in, const int* in_sizes, int n_in,
                              void* d_out, int out_size, void* d_ws, size_t ws_size,
                              hipStream_t stream) {
  (void)in_sizes; (void)n_in; (void)out_size; (void)ws_size;
  const float* x      = (const float*)d_in[0];
  const float* ln_g   = (const float*)d_in[1];
  const float* ln_b   = (const float*)d_in[2];
  const float* W_left = (const float*)d_in[3];
  const float* b_left = (const float*)d_in[4];
  const float* W_right= (const float*)d_in[5];
  const float* b_right= (const float*)d_in[6];
  const float* Wi     = (const float*)d_in[7];
  const float* bi     = (const float*)d_in[8];
  const float* Wf     = (const float*)d_in[9];
  const float* bf     = (const float*)d_in[10];
  const float* Wo     = (const float*)d_in[11];
  const float* bo     = (const float*)d_in[12];
  const float* Wq     = (const float*)d_in[13];
  const float* Wk     = (const float*)d_in[14];
  const float* Wv     = (const float*)d_in[15];
  const float* conv_w = (const float*)d_in[16];
  const float* conv_b = (const float*)d_in[17];
  const float* skip_W = (const float*)d_in[18];
  const float* gn_g   = (const float*)d_in[19];
  const float* gn_b   = (const float*)d_in[20];
  const float* W_last = (const float*)d_in[21];
  const float* b_last = (const float*)d_in[22];
  float* out = (float*)d_out;

  float* ws = (float*)d_ws;
  float* xn   = ws;                  // 262144
  float* xl   = ws + 262144;         // 524288
  float* xr   = ws + 786432;         // 524288
  float* xt   = ws + 1310720;        // 524288
  float* og   = ws + 1835008;        // 524288
  float* vv   = ws + 2359296;        // 524288
  float* qq   = ws + 2883584;        // 524288
  float* kk   = ws + 3407872;        // 524288
  float* sk   = ws + 3932160;        // 524288
  float* hs   = ws + 4456448;        // 524288
  float* ibar = ws + 4980736;        // 1024
  float* fbar = ws + 4981760;        // 1024
  float* gmu  = ws + 4982784;        // 16
  float* grs  = ws + 4982800;        // 16
  float* Gd   = ws + 4982816;        // 1024
  float* Mxd  = ws + 4983840;        // 1024

  k_ln    <<<BT, 256, 0, stream>>>(x, ln_g, ln_b, xn);
  k_lr    <<<BT/8, 512, 0, stream>>>(xn, W_left, b_left, W_right, b_right, xl, xr);
  k_if    <<<BT, 64, 0, stream>>>(xl, Wi, bi, Wf, bf, ibar, fbar);
  k_decay <<<Bz, 256, 0, stream>>>(ibar, fbar, Gd, Mxd);
  k_conv  <<<dim3(BT/8, 2), 256, 0, stream>>>(xl, conv_w, conv_b, xt);
  k_wov   <<<BT/4, 256, 0, stream>>>(xl, Wo, bo, Wv, og, vv);
  k_qks   <<<BT/4, 256, 0, stream>>>(xt, Wq, Wk, skip_W, qq, kk, sk);
  k_attn  <<<dim3(Tz/TTa, Bz), 256, 0, stream>>>(qq, kk, vv, og, Gd, Mxd, hs);
  k_gnstat<<<Bz*Hz, 256, 0, stream>>>(hs, gmu, grs);
  k_final <<<BT/4, 256, 0, stream>>>(hs, gmu, grs, gn_g, gn_b, sk, xr, W_last, b_last, x, out);
}